// Round 2
// baseline (482.734 us; speedup 1.0000x reference)
//
#include <hip/hip_runtime.h>
#include <hip/hip_cooperative_groups.h>

namespace cg = cooperative_groups;

#define NS 10
#define PACKB 2592  // (2*2*256*576 + 2*64*576) / 256

typedef __attribute__((ext_vector_type(8))) short bf16x8;
typedef __attribute__((ext_vector_type(4))) float f32x4;

__device__ __forceinline__ float bf2f(unsigned short u) {
  union { unsigned int i; float f; } x;
  x.i = ((unsigned int)u) << 16;
  return x.f;
}
__device__ __forceinline__ unsigned short f2bf(float f) {
  union { float f; unsigned int i; } x; x.f = f;
  unsigned int r = x.i + 0x7FFFu + ((x.i >> 16) & 1u);
  return (unsigned short)(r >> 16);
}
__device__ __forceinline__ unsigned pk2(float a, float b) {
  return (unsigned)f2bf(a) | ((unsigned)f2bf(b) << 16);
}

struct GJob {
  const float* table; const int* idx; unsigned short* out;
  int M, D4, ns, ostride, blk0; float inv;
};
struct GJobs { GJob j[14]; };

// ===================== phase bodies (shared by fused + fallback) ============

// ---- P0: weight pack (fp32 [K][N] -> bf16 [N][K]) + all input gathers ----
__device__ void gprep_block(
    int b, const GJobs& js, int njobs,
    const float* Wself, const float* Wneigh, const float* Wedg, const float* Wec,
    unsigned short* wt1, unsigned short* wte, int tid) {
  if (b < PACKB) {
    int t = b * 256 + tid;
    const int total1 = 2 * 2 * 256 * 576;
    if (t < total1) {
      int g = t / 147456, r = t - g * 147456;
      int n = r / 576, k = r - n * 576;
      float v;
      if (k < 256) v = Wself[(long)g * 65536 + k * 256 + n];
      else if (k < 512) v = Wneigh[(long)g * 65536 + (k - 256) * 256 + n];
      else v = Wedg[(long)g * 16384 + (k - 512) * 256 + n];
      wt1[t] = f2bf(v);
    } else {
      int t2 = t - total1;  // < 2*64*576
      int mp = t2 / 36864, r = t2 - mp * 36864;
      int n = r / 576, k = r - n * 576;
      wte[t2] = f2bf(Wec[(long)(mp * 2) * 36864 + k * 64 + n]);
    }
    return;
  }
  b -= PACKB;
  int ji = 0;
  for (int k = 1; k < njobs; ++k) if (b >= js.j[k].blk0) ji = k;
  GJob jb = js.j[ji];
  int t = (b - jb.blk0) * 256 + tid;
  int m = t / jb.D4, d4 = t - m * jb.D4;
  long D = (long)jb.D4 * 4;
  float ax = 0.f, ay = 0.f, az = 0.f, aw = 0.f;
  if (jb.ns == NS) {
    int ridx[NS];
#pragma unroll
    for (int s = 0; s < NS; ++s) ridx[s] = jb.idx[(long)m * NS + s];
#pragma unroll
    for (int s = 0; s < NS; ++s) {
      float4 v = *(const float4*)(jb.table + (long)ridx[s] * D + d4 * 4);
      ax += v.x; ay += v.y; az += v.z; aw += v.w;
    }
  } else {
    long r = (long)jb.idx[m];
    float4 v = *(const float4*)(jb.table + r * D + d4 * 4);
    ax = v.x; ay = v.y; az = v.z; aw = v.w;
  }
  uint2 o; o.x = pk2(ax * jb.inv, ay * jb.inv); o.y = pk2(az * jb.inv, aw * jb.inv);
  *(uint2*)(jb.out + (long)m * jb.ostride + d4 * 4) = o;
}

// ---- P1: h01 = relu(A1b @ WT1[mp][0]); BM=64 BN=128, dbuf 1-barrier.
// Tees rows<512 into A3[mp][512][576] cols 0..255.
__device__ void gemm1_tile(int tile, const unsigned short* A, const unsigned short* wt1,
                           unsigned short* C, unsigned short* A3,
                           unsigned short* sm, int tid) {
  unsigned short* As = sm;         // [2][2560]
  unsigned short* Bs = sm + 5120;  // [2][5120]
  int mp = tile & 1, t2 = tile >> 1;
  int n0 = (t2 & 1) * 128, m0 = (t2 >> 1) * 64;
  const unsigned short* Ap = A + (long)mp * (5632L * 576) + (long)m0 * 576;
  const unsigned short* Bp = wt1 + (long)mp * 2 * 147456 + (long)n0 * 576;
  int arow = tid >> 2, aq = tid & 3;
  int bcol = tid >> 1, bh = tid & 1;
  const unsigned short* apt = Ap + (long)arow * 576 + aq * 8;
  const unsigned short* bpt = Bp + (long)bcol * 576 + bh * 16;
  {
    uint4 a = *(const uint4*)apt;
    uint4 b0 = *(const uint4*)bpt, b1 = *(const uint4*)(bpt + 8);
    *(uint4*)&As[arow * 40 + aq * 8] = a;
    *(uint4*)&Bs[bcol * 40 + bh * 16] = b0;
    *(uint4*)&Bs[bcol * 40 + bh * 16 + 8] = b1;
  }
  __syncthreads();

  f32x4 acc[2][4];
#pragma unroll
  for (int i = 0; i < 2; ++i)
#pragma unroll
    for (int j = 0; j < 4; ++j) acc[i][j] = (f32x4){0.f, 0.f, 0.f, 0.f};

  int wave = tid >> 6, lane = tid & 63;
  int wm = wave >> 1, wn = wave & 1;
  int quad = lane >> 4, r16 = lane & 15;

  for (int it = 0; it < 18; ++it) {
    uint4 na, nb0, nb1;
    bool pf = (it + 1 < 18);
    if (pf) {
      na  = *(const uint4*)(apt + (it + 1) * 32);
      nb0 = *(const uint4*)(bpt + (it + 1) * 32);
      nb1 = *(const uint4*)(bpt + (it + 1) * 32 + 8);
    }
    int c = it & 1;
    bf16x8 af[2], bfr[4];
#pragma unroll
    for (int i = 0; i < 2; ++i)
      af[i] = *(const bf16x8*)&As[c * 2560 + (wm * 32 + i * 16 + r16) * 40 + quad * 8];
#pragma unroll
    for (int j = 0; j < 4; ++j)
      bfr[j] = *(const bf16x8*)&Bs[c * 5120 + (wn * 64 + j * 16 + r16) * 40 + quad * 8];
#pragma unroll
    for (int i = 0; i < 2; ++i)
#pragma unroll
      for (int j = 0; j < 4; ++j)
        acc[i][j] = __builtin_amdgcn_mfma_f32_16x16x32_bf16(af[i], bfr[j], acc[i][j], 0, 0, 0);
    if (pf) {
      *(uint4*)&As[(c ^ 1) * 2560 + arow * 40 + aq * 8] = na;
      *(uint4*)&Bs[(c ^ 1) * 5120 + bcol * 40 + bh * 16] = nb0;
      *(uint4*)&Bs[(c ^ 1) * 5120 + bcol * 40 + bh * 16 + 8] = nb1;
      __syncthreads();
    }
  }
#pragma unroll
  for (int i = 0; i < 2; ++i)
#pragma unroll
    for (int j = 0; j < 4; ++j)
#pragma unroll
      for (int r = 0; r < 4; ++r) {
        int row = m0 + wm * 32 + i * 16 + quad * 4 + r;
        int col = n0 + wn * 64 + j * 16 + r16;
        unsigned short u = f2bf(fmaxf(acc[i][j][r], 0.f));
        C[(long)mp * (5632L * 256) + (long)row * 256 + col] = u;
        if (row < 512)
          A3[(long)mp * (512L * 576) + (long)row * 576 + col] = u;
      }
}

// ---- P2a: edge GEMM enew = tanh([h0(rep10)|h1|eg0] @ WTe + be); dbuf ----
__device__ __forceinline__ const unsigned short* edgeA(
    const unsigned short* h0, const unsigned short* h1, const unsigned short* eg,
    int ar0, int gr, int q, int it) {
  if (it < 8)  return h0 + (long)ar0 * 256 + it * 32 + q * 8;
  if (it < 16) return h1 + (long)gr * 256 + (it - 8) * 32 + q * 8;
  return eg + (long)gr * 64 + (it - 16) * 32 + q * 8;
}

__device__ void edge_tile(int tile, const unsigned short* h01, const unsigned short* eg0,
                          const unsigned short* wte, const float* bec,
                          unsigned short* enew, unsigned short* sm, int tid) {
  unsigned short* As = sm;         // [2][2560]
  unsigned short* Bs = sm + 5120;  // [2][2560]
  int mp = tile & 1;
  int m0 = (tile >> 1) * 64;
  const unsigned short* h0 = h01 + (long)mp * (5632L * 256);
  const unsigned short* h1 = h0 + 512 * 256;
  const unsigned short* eg = eg0 + (long)mp * (5120L * 64);
  const unsigned short* Bp = wte + (long)mp * 36864;

  int row = tid >> 2, q = tid & 3;
  int gr = m0 + row;
  int ar0 = gr / 10;
  const unsigned short* bpt = Bp + (long)row * 576 + q * 8;

  {
    uint4 a = *(const uint4*)edgeA(h0, h1, eg, ar0, gr, q, 0);
    uint4 bv = *(const uint4*)bpt;
    *(uint4*)&As[row * 40 + q * 8] = a;
    *(uint4*)&Bs[row * 40 + q * 8] = bv;
  }
  __syncthreads();

  f32x4 acc[2][2];
#pragma unroll
  for (int i = 0; i < 2; ++i)
#pragma unroll
    for (int j = 0; j < 2; ++j) acc[i][j] = (f32x4){0.f, 0.f, 0.f, 0.f};

  int wave = tid >> 6, lane = tid & 63;
  int wm = wave >> 1, wn = wave & 1;
  int quad = lane >> 4, r16 = lane & 15;

  for (int it = 0; it < 18; ++it) {
    uint4 na, nb;
    bool pf = (it + 1 < 18);
    if (pf) {
      na = *(const uint4*)edgeA(h0, h1, eg, ar0, gr, q, it + 1);
      nb = *(const uint4*)(bpt + (it + 1) * 32);
    }
    int c = it & 1;
    bf16x8 af[2], bfr[2];
#pragma unroll
    for (int i = 0; i < 2; ++i)
      af[i] = *(const bf16x8*)&As[c * 2560 + (wm * 32 + i * 16 + r16) * 40 + quad * 8];
#pragma unroll
    for (int j = 0; j < 2; ++j)
      bfr[j] = *(const bf16x8*)&Bs[c * 2560 + (wn * 32 + j * 16 + r16) * 40 + quad * 8];
#pragma unroll
    for (int i = 0; i < 2; ++i)
#pragma unroll
      for (int j = 0; j < 2; ++j)
        acc[i][j] = __builtin_amdgcn_mfma_f32_16x16x32_bf16(af[i], bfr[j], acc[i][j], 0, 0, 0);
    if (pf) {
      *(uint4*)&As[(c ^ 1) * 2560 + row * 40 + q * 8] = na;
      *(uint4*)&Bs[(c ^ 1) * 2560 + row * 40 + q * 8] = nb;
      __syncthreads();
    }
  }
#pragma unroll
  for (int i = 0; i < 2; ++i)
#pragma unroll
    for (int j = 0; j < 2; ++j)
#pragma unroll
      for (int r = 0; r < 4; ++r) {
        int rr = m0 + wm * 32 + i * 16 + quad * 4 + r;
        int cc = wn * 32 + j * 16 + r16;
        float v = tanhf(acc[i][j][r] + bec[mp * 128 + cc]);
        enew[(long)mp * (5120L * 64) + (long)rr * 64 + cc] = f2bf(v);
      }
}

// ---- P2b/P3: A3[mp][m][256..511] = mean10(h1); [512..575] = mean10(enew) ----
__device__ __forceinline__ void h1mean_item(int t, const unsigned short* h01,
                                            unsigned short* A3) {
  // t in [0, 32768): mp = t>>14, m = (t&16383)>>5, d8 = t&31
  int mp = t >> 14, t14 = t & 16383;
  int m = t14 >> 5, d8 = t14 & 31;
  const unsigned short* h1 = h01 + (long)mp * (5632L * 256) + 512 * 256;
  float s[8];
#pragma unroll
  for (int x = 0; x < 8; ++x) s[x] = 0.f;
#pragma unroll
  for (int ss = 0; ss < NS; ++ss) {
    uint4 v = *(const uint4*)(h1 + (long)(m * NS + ss) * 256 + d8 * 8);
    unsigned vals[4] = {v.x, v.y, v.z, v.w};
#pragma unroll
    for (int x = 0; x < 4; ++x) {
      s[x * 2]     += bf2f((unsigned short)(vals[x] & 0xFFFF));
      s[x * 2 + 1] += bf2f((unsigned short)(vals[x] >> 16));
    }
  }
  uint4 o;
  o.x = pk2(s[0] * 0.1f, s[1] * 0.1f);
  o.y = pk2(s[2] * 0.1f, s[3] * 0.1f);
  o.z = pk2(s[4] * 0.1f, s[5] * 0.1f);
  o.w = pk2(s[6] * 0.1f, s[7] * 0.1f);
  *(uint4*)(A3 + (long)mp * (512L * 576) + (long)m * 576 + 256 + d8 * 8) = o;
}

__device__ __forceinline__ void emean_item(int t, const unsigned short* enew,
                                           unsigned short* A3) {
  // t in [0, 8192): mp = t>>12, m = (t&4095)>>3, d8 = t&7
  int mp = t >> 12, t12 = t & 4095;
  int m = t12 >> 3, d8 = t12 & 7;
  const unsigned short* en = enew + (long)mp * (5120L * 64);
  float s[8];
#pragma unroll
  for (int x = 0; x < 8; ++x) s[x] = 0.f;
#pragma unroll
  for (int ss = 0; ss < NS; ++ss) {
    uint4 v = *(const uint4*)(en + (long)(m * NS + ss) * 64 + d8 * 8);
    unsigned vals[4] = {v.x, v.y, v.z, v.w};
#pragma unroll
    for (int x = 0; x < 4; ++x) {
      s[x * 2]     += bf2f((unsigned short)(vals[x] & 0xFFFF));
      s[x * 2 + 1] += bf2f((unsigned short)(vals[x] >> 16));
    }
  }
  uint4 o;
  o.x = pk2(s[0] * 0.1f, s[1] * 0.1f);
  o.y = pk2(s[2] * 0.1f, s[3] * 0.1f);
  o.z = pk2(s[4] * 0.1f, s[5] * 0.1f);
  o.w = pk2(s[6] * 0.1f, s[7] * 0.1f);
  *(uint4*)(A3 + (long)mp * (512L * 576) + (long)m * 576 + 512 + d8 * 8) = o;
}

// ---- P4: osum = A3 @ WT1[mp][1]; BM=64 BN=64, dbuf, fp32 out ----
__device__ void gemm3_tile(int tile, const unsigned short* A3, const unsigned short* wt1,
                           float* osum, unsigned short* sm, int tid) {
  unsigned short* As = sm;         // [2][2560]
  unsigned short* Bs = sm + 5120;  // [2][2560]
  int mp = tile & 1, t2 = tile >> 1;
  int n0 = (t2 & 3) * 64, m0 = (t2 >> 2) * 64;
  const unsigned short* Ap = A3 + (long)mp * (512L * 576) + (long)m0 * 576;
  const unsigned short* Bp = wt1 + (long)(mp * 2 + 1) * 147456 + (long)n0 * 576;

  int row = tid >> 2, q = tid & 3;
  const unsigned short* apt = Ap + (long)row * 576 + q * 8;
  const unsigned short* bpt = Bp + (long)row * 576 + q * 8;

  {
    uint4 a = *(const uint4*)apt;
    uint4 bv = *(const uint4*)bpt;
    *(uint4*)&As[row * 40 + q * 8] = a;
    *(uint4*)&Bs[row * 40 + q * 8] = bv;
  }
  __syncthreads();

  f32x4 acc[2][2];
#pragma unroll
  for (int i = 0; i < 2; ++i)
#pragma unroll
    for (int j = 0; j < 2; ++j) acc[i][j] = (f32x4){0.f, 0.f, 0.f, 0.f};

  int wave = tid >> 6, lane = tid & 63;
  int wm = wave >> 1, wn = wave & 1;
  int quad = lane >> 4, r16 = lane & 15;

  for (int it = 0; it < 18; ++it) {
    uint4 na, nb;
    bool pf = (it + 1 < 18);
    if (pf) {
      na = *(const uint4*)(apt + (it + 1) * 32);
      nb = *(const uint4*)(bpt + (it + 1) * 32);
    }
    int c = it & 1;
    bf16x8 af[2], bfr[2];
#pragma unroll
    for (int i = 0; i < 2; ++i)
      af[i] = *(const bf16x8*)&As[c * 2560 + (wm * 32 + i * 16 + r16) * 40 + quad * 8];
#pragma unroll
    for (int j = 0; j < 2; ++j)
      bfr[j] = *(const bf16x8*)&Bs[c * 2560 + (wn * 32 + j * 16 + r16) * 40 + quad * 8];
#pragma unroll
    for (int i = 0; i < 2; ++i)
#pragma unroll
      for (int j = 0; j < 2; ++j)
        acc[i][j] = __builtin_amdgcn_mfma_f32_16x16x32_bf16(af[i], bfr[j], acc[i][j], 0, 0, 0);
    if (pf) {
      *(uint4*)&As[(c ^ 1) * 2560 + row * 40 + q * 8] = na;
      *(uint4*)&Bs[(c ^ 1) * 2560 + row * 40 + q * 8] = nb;
      __syncthreads();
    }
  }
#pragma unroll
  for (int i = 0; i < 2; ++i)
#pragma unroll
    for (int j = 0; j < 2; ++j)
#pragma unroll
      for (int r = 0; r < 4; ++r) {
        int rr = m0 + wm * 32 + i * 16 + quad * 4 + r;
        int cc = n0 + wn * 32 + j * 16 + r16;
        osum[(long)mp * 131072 + (long)rr * 256 + cc] = acc[i][j][r];
      }
}

// ---- P5: out = normalize((o0+o1)/2) @ fc_w + fc_b; one wave per row ----
__device__ void finalize_rows(int tile, const float* osum, const float* fcw,
                              const float* fcb, float* out, int tid) {
  int wave = tid >> 6, l = tid & 63;
  int b = tile * 4 + wave;  // < 512 when tile < 128
  const float* o0 = osum;
  const float* o1 = osum + 131072;
  float v[4];
  float ss = 0.f;
#pragma unroll
  for (int k = 0; k < 4; ++k) {
    int j = l + 64 * k;
    v[k] = 0.5f * (o0[(long)b * 256 + j] + o1[(long)b * 256 + j]);
    ss += v[k] * v[k];
  }
#pragma unroll
  for (int off = 32; off > 0; off >>= 1) ss += __shfl_down(ss, off);
  ss = __shfl(ss, 0);
  float sc = 1.f / fmaxf(sqrtf(ss), 1e-12f);
  float p[8];
#pragma unroll
  for (int c = 0; c < 8; ++c) p[c] = 0.f;
#pragma unroll
  for (int k = 0; k < 4; ++k) {
    int j = l + 64 * k;
    float vh = v[k] * sc;
#pragma unroll
    for (int c = 0; c < 8; ++c) p[c] += vh * fcw[j * 8 + c];
  }
#pragma unroll
  for (int off = 32; off > 0; off >>= 1) {
#pragma unroll
    for (int c = 0; c < 8; ++c) p[c] += __shfl_down(p[c], off);
  }
  if (l == 0) {
#pragma unroll
    for (int c = 0; c < 8; ++c) out[b * 8 + c] = p[c] + fcb[c];
  }
}

// ===================== fused cooperative kernel =============================
__global__ __launch_bounds__(256, 3) void fused_k(
    GJobs js, int njobs, int gblocks,
    const float* Wself, const float* Wneigh, const float* Wedg, const float* Wec,
    unsigned short* wt1, unsigned short* wte, unsigned short* A1b,
    const float* bec, const float* fcw, const float* fcb,
    unsigned short* h01, unsigned short* A3, unsigned short* eg0,
    unsigned short* enew, float* osum, float* out) {
  __shared__ unsigned short sm[15360];  // 30720 B: max phase need (gemm1)
  int tid = threadIdx.x;
  cg::grid_group grid = cg::this_grid();

  // P0: weight pack + gathers
  for (int b = blockIdx.x; b < gblocks; b += gridDim.x)
    gprep_block(b, js, njobs, Wself, Wneigh, Wedg, Wec, wt1, wte, tid);
  grid.sync();

  // P1: layer-0 agg (352 tiles)
  for (int t = blockIdx.x; t < 352; t += gridDim.x)
    gemm1_tile(t, A1b, wt1, h01, A3, sm, tid);
  grid.sync();

  // P2: edge GEMM (160 tiles) || h1-means (128 block-jobs)
  for (int j = blockIdx.x; j < 288; j += gridDim.x) {
    if (j < 160) edge_tile(j, h01, eg0, wte, bec, enew, sm, tid);
    else h1mean_item((j - 160) * 256 + tid, h01, A3);
  }
  grid.sync();

  // P3: enew-means (8192 items)
  for (int t = blockIdx.x * 256 + tid; t < 8192; t += gridDim.x * 256)
    emean_item(t, enew, A3);
  grid.sync();

  // P4: layer-1 agg (64 tiles)
  for (int t = blockIdx.x; t < 64; t += gridDim.x)
    gemm3_tile(t, A3, wt1, osum, sm, tid);
  grid.sync();

  // P5: finalize (128 tiles x 4 rows)
  for (int t = blockIdx.x; t < 128; t += gridDim.x)
    finalize_rows(t, osum, fcw, fcb, out, tid);
}

// ===================== non-cooperative fallback kernels =====================
__global__ __launch_bounds__(256) void gprep_sk(
    GJobs js, int njobs, int gblocks,
    const float* Wself, const float* Wneigh, const float* Wedg, const float* Wec,
    unsigned short* wt1, unsigned short* wte) {
  gprep_block(blockIdx.x, js, njobs, Wself, Wneigh, Wedg, Wec, wt1, wte, threadIdx.x);
}
__global__ __launch_bounds__(256) void gemm1_sk(
    const unsigned short* A, const unsigned short* wt1,
    unsigned short* C, unsigned short* A3) {
  __shared__ unsigned short sm[15360];
  gemm1_tile(blockIdx.x, A, wt1, C, A3, sm, threadIdx.x);
}
__global__ __launch_bounds__(256) void edge_sk(
    const unsigned short* h01, const unsigned short* eg0,
    const unsigned short* wte, const float* bec, unsigned short* enew) {
  __shared__ unsigned short sm[15360];
  edge_tile(blockIdx.x, h01, eg0, wte, bec, enew, sm, threadIdx.x);
}
__global__ __launch_bounds__(256) void mean_sk(
    const unsigned short* h01, const unsigned short* enew, unsigned short* A3) {
  int t = blockIdx.x * 256 + threadIdx.x;
  if (t < 32768) h1mean_item(t, h01, A3);
  else emean_item(t - 32768, enew, A3);
}
__global__ __launch_bounds__(256) void gemm3_sk(
    const unsigned short* A3, const unsigned short* wt1, float* osum) {
  __shared__ unsigned short sm[15360];
  gemm3_tile(blockIdx.x, A3, wt1, osum, sm, threadIdx.x);
}
__global__ __launch_bounds__(256) void finalize_sk(
    const float* osum, const float* fcw, const float* fcb, float* out) {
  finalize_rows(blockIdx.x, osum, fcw, fcb, out, threadIdx.x);
}

extern "C" void kernel_launch(void* const* d_in, const int* in_sizes, int n_in,
                              void* d_out, int out_size, void* d_ws, size_t ws_size,
                              hipStream_t stream) {
  const int* ids = (const int*)d_in[0];
  const float* feats = (const float*)d_in[1];
  const int* n0i[2] = {(const int*)d_in[2], (const int*)d_in[4]};
  const int* n1i[2] = {(const int*)d_in[3], (const int*)d_in[5]};
  const int* e0i[2] = {(const int*)d_in[6], (const int*)d_in[8]};
  const int* e1i[2] = {(const int*)d_in[7], (const int*)d_in[9]};
  const float* emb[2] = {(const float*)d_in[10], (const float*)d_in[11]};
  const float* Wself = (const float*)d_in[12];
  const float* Wneigh = (const float*)d_in[13];
  const float* Wedg = (const float*)d_in[14];
  const float* Wec = (const float*)d_in[15];
  const float* bec = (const float*)d_in[16];
  const float* fcw = (const float*)d_in[17];
  const float* fcb = (const float*)d_in[18];
  float* out = (float*)d_out;

  // ---- workspace ----
  float* osum = (float*)d_ws;                               // [2][512][256] f32
  unsigned short* A1b  = (unsigned short*)(osum + 262144);  // [2][5632][576]
  unsigned short* eg0  = A1b + 6488064;                     // [2][5120][64]
  unsigned short* h01  = eg0 + 655360;                      // [2][5632][256]
  unsigned short* enew = h01 + 2883584;                     // [2][5120][64]
  unsigned short* wt1  = enew + 655360;                     // [4][256][576]
  unsigned short* wte  = wt1 + 589824;                      // [2][64][576]
  unsigned short* A3   = wte + 73728;                       // [2][512][576]

  // ---- gather job table ----
  GJobs gj; int blk = 0; int nj = 0;
  {
    auto add = [&](const float* table, const int* idx, unsigned short* o,
                   int M, int D4, int ns, int ostride, float inv) {
      gj.j[nj] = {table, idx, o, M, D4, ns, ostride, blk, inv};
      blk += (M * D4) / 256; ++nj;
    };
    for (int mp = 0; mp < 2; ++mp) {
      unsigned short* Am = A1b + (size_t)mp * 5632 * 576;
      add(feats, ids,     Am,                     512, 64, 1, 576, 1.0f);
      add(feats, n0i[mp], Am + 512 * 576,         5120, 64, 1, 576, 1.0f);
      add(feats, n0i[mp], Am + 256,               512, 64, NS, 576, 0.1f);
      add(feats, n1i[mp], Am + 512 * 576 + 256,   5120, 64, NS, 576, 0.1f);
      add(emb[mp], e0i[mp], Am + 512,             512, 16, NS, 576, 0.1f);
      add(emb[mp], e1i[mp], Am + 512 * 576 + 512, 5120, 16, NS, 576, 0.1f);
      add(emb[mp], e0i[mp], eg0 + (size_t)mp * 327680, 5120, 16, 1, 64, 1.0f);
    }
  }
  int gblocks = PACKB + blk;

  // ---- cooperative grid size (cached); 0 => fallback ----
  static int coopBlocks = -1;
  if (coopBlocks < 0) {
    int bpc = 0;
    hipError_t e = hipOccupancyMaxActiveBlocksPerMultiprocessor(
        &bpc, reinterpret_cast<const void*>(&fused_k), 256, 0);
    if (e != hipSuccess || bpc < 1) coopBlocks = 0;
    else {
      if (bpc > 3) bpc = 3;
      coopBlocks = bpc * 256;  // MI355X: 256 CUs
    }
  }

  bool launched = false;
  if (coopBlocks > 0) {
    void* args[] = {&gj, &nj, &gblocks, &Wself, &Wneigh, &Wedg, &Wec,
                    &wt1, &wte, &A1b, &bec, &fcw, &fcb, &h01, &A3, &eg0,
                    &enew, &osum, &out};
    hipError_t e = hipLaunchCooperativeKernel(
        reinterpret_cast<const void*>(&fused_k), dim3(coopBlocks), dim3(256),
        args, 0, stream);
    if (e == hipSuccess) launched = true;
    else coopBlocks = 0;  // don't retry
  }

  if (!launched) {
    gprep_sk<<<dim3(gblocks), dim3(256), 0, stream>>>(
        gj, nj, gblocks, Wself, Wneigh, Wedg, Wec, wt1, wte);
    gemm1_sk<<<dim3(352), dim3(256), 0, stream>>>(A1b, wt1, h01, A3);
    edge_sk<<<dim3(160), dim3(256), 0, stream>>>(h01, eg0, wte, bec, enew);
    mean_sk<<<dim3(160), dim3(256), 0, stream>>>(h01, enew, A3);
    gemm3_sk<<<dim3(64), dim3(256), 0, stream>>>(A3, wt1, osum);
    finalize_sk<<<dim3(128), dim3(256), 0, stream>>>(osum, fcw, fcb, out);
  }
}

// Round 3
// 272.027 us; speedup vs baseline: 1.7746x; 1.7746x over previous
//
#include <hip/hip_runtime.h>

#define NS 10
#define PACKB 2592  // (2*2*256*576 + 2*64*576) / 256

typedef __attribute__((ext_vector_type(8))) short bf16x8;
typedef __attribute__((ext_vector_type(4))) float f32x4;

__device__ __forceinline__ float bf2f(unsigned short u) {
  union { unsigned int i; float f; } x;
  x.i = ((unsigned int)u) << 16;
  return x.f;
}
__device__ __forceinline__ unsigned short f2bf(float f) {
  union { float f; unsigned int i; } x; x.f = f;
  unsigned int r = x.i + 0x7FFFu + ((x.i >> 16) & 1u);
  return (unsigned short)(r >> 16);
}
__device__ __forceinline__ unsigned pk2(float a, float b) {
  return (unsigned)f2bf(a) | ((unsigned)f2bf(b) << 16);
}

// ===== gprep: weight pack + gathers; dual jobs write direct rows AND mean ===
struct GJob {
  const float* table; const int* idx;
  unsigned short* out; unsigned short* out2;   // out2: direct rows (dual jobs)
  int M, D4, ns, ostride, ostride2, blk0; float inv;
};
struct GJobs { GJob j[10]; };

__global__ __launch_bounds__(256) void gprep_k(
    GJobs js, int njobs,
    const float* __restrict__ Wself, const float* __restrict__ Wneigh,
    const float* __restrict__ Wedg, const float* __restrict__ Wec,
    unsigned short* __restrict__ wt1, unsigned short* __restrict__ wte) {
  int b = blockIdx.x;
  if (b < PACKB) {
    int t = b * 256 + threadIdx.x;
    const int total1 = 2 * 2 * 256 * 576;
    if (t < total1) {
      int g = t / 147456, r = t - g * 147456;
      int n = r / 576, k = r - n * 576;
      float v;
      if (k < 256) v = Wself[(long)g * 65536 + k * 256 + n];
      else if (k < 512) v = Wneigh[(long)g * 65536 + (k - 256) * 256 + n];
      else v = Wedg[(long)g * 16384 + (k - 512) * 256 + n];
      wt1[t] = f2bf(v);
    } else {
      int t2 = t - total1;  // < 2*64*576
      int mp = t2 / 36864, r = t2 - mp * 36864;
      int n = r / 576, k = r - n * 576;
      wte[t2] = f2bf(Wec[(long)(mp * 2) * 36864 + k * 64 + n]);
    }
    return;
  }
  b -= PACKB;
  int ji = 0;
  for (int k = 1; k < njobs; ++k) if (b >= js.j[k].blk0) ji = k;
  GJob jb = js.j[ji];
  int t = (b - jb.blk0) * 256 + threadIdx.x;
  int m = t / jb.D4, d4 = t - m * jb.D4;
  long D = (long)jb.D4 * 4;
  float ax = 0.f, ay = 0.f, az = 0.f, aw = 0.f;
  if (jb.ns == NS) {
    int ridx[NS];
#pragma unroll
    for (int s = 0; s < NS; ++s) ridx[s] = jb.idx[(long)m * NS + s];
    float4 vv[NS];
#pragma unroll
    for (int s = 0; s < NS; ++s)
      vv[s] = *(const float4*)(jb.table + (long)ridx[s] * D + d4 * 4);
#pragma unroll
    for (int s = 0; s < NS; ++s) {
      ax += vv[s].x; ay += vv[s].y; az += vv[s].z; aw += vv[s].w;
    }
    if (jb.out2) {  // dual: also emit the 10 direct rows (scale 1.0)
#pragma unroll
      for (int s = 0; s < NS; ++s) {
        uint2 o2; o2.x = pk2(vv[s].x, vv[s].y); o2.y = pk2(vv[s].z, vv[s].w);
        *(uint2*)(jb.out2 + (long)(m * NS + s) * jb.ostride2 + d4 * 4) = o2;
      }
    }
  } else {
    long r = (long)jb.idx[m];
    float4 v = *(const float4*)(jb.table + r * D + d4 * 4);
    ax = v.x; ay = v.y; az = v.z; aw = v.w;
  }
  uint2 o; o.x = pk2(ax * jb.inv, ay * jb.inv); o.y = pk2(az * jb.inv, aw * jb.inv);
  *(uint2*)(jb.out + (long)m * jb.ostride + d4 * 4) = o;
}

// ===== GEMM1: h01 = relu(A1b @ WT1[mp][0]); BM=64 BN=128, dbuf 1-barrier ====
// Tees rows<512 into A3[mp][512][576] cols 0..255. 352 tiles.
__global__ __launch_bounds__(256) void gemm1_k(
    const unsigned short* __restrict__ A, const unsigned short* __restrict__ wt1,
    unsigned short* __restrict__ C, unsigned short* __restrict__ A3) {
  __shared__ unsigned short sm[15360];
  unsigned short* As = sm;         // [2][2560]
  unsigned short* Bs = sm + 5120;  // [2][5120]
  int tid = threadIdx.x, tile = blockIdx.x;
  int mp = tile & 1, t2 = tile >> 1;
  int n0 = (t2 & 1) * 128, m0 = (t2 >> 1) * 64;
  const unsigned short* Ap = A + (long)mp * (5632L * 576) + (long)m0 * 576;
  const unsigned short* Bp = wt1 + (long)mp * 2 * 147456 + (long)n0 * 576;
  int arow = tid >> 2, aq = tid & 3;
  int bcol = tid >> 1, bh = tid & 1;
  const unsigned short* apt = Ap + (long)arow * 576 + aq * 8;
  const unsigned short* bpt = Bp + (long)bcol * 576 + bh * 16;
  {
    uint4 a = *(const uint4*)apt;
    uint4 b0 = *(const uint4*)bpt, b1 = *(const uint4*)(bpt + 8);
    *(uint4*)&As[arow * 40 + aq * 8] = a;
    *(uint4*)&Bs[bcol * 40 + bh * 16] = b0;
    *(uint4*)&Bs[bcol * 40 + bh * 16 + 8] = b1;
  }
  __syncthreads();

  f32x4 acc[2][4];
#pragma unroll
  for (int i = 0; i < 2; ++i)
#pragma unroll
    for (int j = 0; j < 4; ++j) acc[i][j] = (f32x4){0.f, 0.f, 0.f, 0.f};

  int wave = tid >> 6, lane = tid & 63;
  int wm = wave >> 1, wn = wave & 1;
  int quad = lane >> 4, r16 = lane & 15;

  for (int it = 0; it < 18; ++it) {
    uint4 na, nb0, nb1;
    bool pf = (it + 1 < 18);
    if (pf) {
      na  = *(const uint4*)(apt + (it + 1) * 32);
      nb0 = *(const uint4*)(bpt + (it + 1) * 32);
      nb1 = *(const uint4*)(bpt + (it + 1) * 32 + 8);
    }
    int c = it & 1;
    bf16x8 af[2], bfr[4];
#pragma unroll
    for (int i = 0; i < 2; ++i)
      af[i] = *(const bf16x8*)&As[c * 2560 + (wm * 32 + i * 16 + r16) * 40 + quad * 8];
#pragma unroll
    for (int j = 0; j < 4; ++j)
      bfr[j] = *(const bf16x8*)&Bs[c * 5120 + (wn * 64 + j * 16 + r16) * 40 + quad * 8];
#pragma unroll
    for (int i = 0; i < 2; ++i)
#pragma unroll
      for (int j = 0; j < 4; ++j)
        acc[i][j] = __builtin_amdgcn_mfma_f32_16x16x32_bf16(af[i], bfr[j], acc[i][j], 0, 0, 0);
    if (pf) {
      *(uint4*)&As[(c ^ 1) * 2560 + arow * 40 + aq * 8] = na;
      *(uint4*)&Bs[(c ^ 1) * 5120 + bcol * 40 + bh * 16] = nb0;
      *(uint4*)&Bs[(c ^ 1) * 5120 + bcol * 40 + bh * 16 + 8] = nb1;
      __syncthreads();
    }
  }
#pragma unroll
  for (int i = 0; i < 2; ++i)
#pragma unroll
    for (int j = 0; j < 4; ++j)
#pragma unroll
      for (int r = 0; r < 4; ++r) {
        int row = m0 + wm * 32 + i * 16 + quad * 4 + r;
        int col = n0 + wn * 64 + j * 16 + r16;
        unsigned short u = f2bf(fmaxf(acc[i][j][r], 0.f));
        C[(long)mp * (5632L * 256) + (long)row * 256 + col] = u;
        if (row < 512)
          A3[(long)mp * (512L * 576) + (long)row * 576 + col] = u;
      }
}

// ===== P3: edge GEMM (160 tiles) || h1-means (128 block-jobs) ==============
__device__ __forceinline__ const unsigned short* edgeA(
    const unsigned short* h0, const unsigned short* h1, const unsigned short* eg,
    int ar0, int gr, int q, int it) {
  if (it < 8)  return h0 + (long)ar0 * 256 + it * 32 + q * 8;
  if (it < 16) return h1 + (long)gr * 256 + (it - 8) * 32 + q * 8;
  return eg + (long)gr * 64 + (it - 16) * 32 + q * 8;
}

__device__ void edge_tile(int tile, const unsigned short* h01, const unsigned short* eg0,
                          const unsigned short* wte, const float* bec,
                          unsigned short* enew, unsigned short* sm, int tid) {
  unsigned short* As = sm;         // [2][2560]
  unsigned short* Bs = sm + 5120;  // [2][2560]
  int mp = tile & 1;
  int m0 = (tile >> 1) * 64;
  const unsigned short* h0 = h01 + (long)mp * (5632L * 256);
  const unsigned short* h1 = h0 + 512 * 256;
  const unsigned short* eg = eg0 + (long)mp * (5120L * 64);
  const unsigned short* Bp = wte + (long)mp * 36864;

  int row = tid >> 2, q = tid & 3;
  int gr = m0 + row;
  int ar0 = gr / 10;
  const unsigned short* bpt = Bp + (long)row * 576 + q * 8;

  {
    uint4 a = *(const uint4*)edgeA(h0, h1, eg, ar0, gr, q, 0);
    uint4 bv = *(const uint4*)bpt;
    *(uint4*)&As[row * 40 + q * 8] = a;
    *(uint4*)&Bs[row * 40 + q * 8] = bv;
  }
  __syncthreads();

  f32x4 acc[2][2];
#pragma unroll
  for (int i = 0; i < 2; ++i)
#pragma unroll
    for (int j = 0; j < 2; ++j) acc[i][j] = (f32x4){0.f, 0.f, 0.f, 0.f};

  int wave = tid >> 6, lane = tid & 63;
  int wm = wave >> 1, wn = wave & 1;
  int quad = lane >> 4, r16 = lane & 15;

  for (int it = 0; it < 18; ++it) {
    uint4 na, nb;
    bool pf = (it + 1 < 18);
    if (pf) {
      na = *(const uint4*)edgeA(h0, h1, eg, ar0, gr, q, it + 1);
      nb = *(const uint4*)(bpt + (it + 1) * 32);
    }
    int c = it & 1;
    bf16x8 af[2], bfr[2];
#pragma unroll
    for (int i = 0; i < 2; ++i)
      af[i] = *(const bf16x8*)&As[c * 2560 + (wm * 32 + i * 16 + r16) * 40 + quad * 8];
#pragma unroll
    for (int j = 0; j < 2; ++j)
      bfr[j] = *(const bf16x8*)&Bs[c * 2560 + (wn * 32 + j * 16 + r16) * 40 + quad * 8];
#pragma unroll
    for (int i = 0; i < 2; ++i)
#pragma unroll
      for (int j = 0; j < 2; ++j)
        acc[i][j] = __builtin_amdgcn_mfma_f32_16x16x32_bf16(af[i], bfr[j], acc[i][j], 0, 0, 0);
    if (pf) {
      *(uint4*)&As[(c ^ 1) * 2560 + row * 40 + q * 8] = na;
      *(uint4*)&Bs[(c ^ 1) * 2560 + row * 40 + q * 8] = nb;
      __syncthreads();
    }
  }
#pragma unroll
  for (int i = 0; i < 2; ++i)
#pragma unroll
    for (int j = 0; j < 2; ++j)
#pragma unroll
      for (int r = 0; r < 4; ++r) {
        int rr = m0 + wm * 32 + i * 16 + quad * 4 + r;
        int cc = wn * 32 + j * 16 + r16;
        float v = tanhf(acc[i][j][r] + bec[mp * 128 + cc]);
        enew[(long)mp * (5120L * 64) + (long)rr * 64 + cc] = f2bf(v);
      }
}

__device__ __forceinline__ void h1mean_item(int t, const unsigned short* h01,
                                            unsigned short* A3) {
  // t in [0, 32768): mp = t>>14, m = (t&16383)>>5, d8 = t&31
  int mp = t >> 14, t14 = t & 16383;
  int m = t14 >> 5, d8 = t14 & 31;
  const unsigned short* h1 = h01 + (long)mp * (5632L * 256) + 512 * 256;
  float s[8];
#pragma unroll
  for (int x = 0; x < 8; ++x) s[x] = 0.f;
#pragma unroll
  for (int ss = 0; ss < NS; ++ss) {
    uint4 v = *(const uint4*)(h1 + (long)(m * NS + ss) * 256 + d8 * 8);
    unsigned vals[4] = {v.x, v.y, v.z, v.w};
#pragma unroll
    for (int x = 0; x < 4; ++x) {
      s[x * 2]     += bf2f((unsigned short)(vals[x] & 0xFFFF));
      s[x * 2 + 1] += bf2f((unsigned short)(vals[x] >> 16));
    }
  }
  uint4 o;
  o.x = pk2(s[0] * 0.1f, s[1] * 0.1f);
  o.y = pk2(s[2] * 0.1f, s[3] * 0.1f);
  o.z = pk2(s[4] * 0.1f, s[5] * 0.1f);
  o.w = pk2(s[6] * 0.1f, s[7] * 0.1f);
  *(uint4*)(A3 + (long)mp * (512L * 576) + (long)m * 576 + 256 + d8 * 8) = o;
}

__global__ __launch_bounds__(256) void p3_k(
    const unsigned short* __restrict__ h01, const unsigned short* __restrict__ eg0,
    const unsigned short* __restrict__ wte, const float* __restrict__ bec,
    unsigned short* __restrict__ enew, unsigned short* __restrict__ A3) {
  __shared__ unsigned short sm[10240];
  int j = blockIdx.x;
  if (j < 160) edge_tile(j, h01, eg0, wte, bec, enew, sm, threadIdx.x);
  else h1mean_item((j - 160) * 256 + threadIdx.x, h01, A3);
}

// ===== GEMM3: osum = [A3 cols 0..511 | mean10(enew)] @ WT1[mp][1] ==========
// BM=64 BN=64, dbuf; e-mean computed on the fly in the A-stage (it>=16).
__device__ __forceinline__ uint4 g3A(const unsigned short* apt,
                                     const unsigned short* en, int gr, int q, int it) {
  if (it < 16) return *(const uint4*)(apt + it * 32);
  float s[8];
#pragma unroll
  for (int x = 0; x < 8; ++x) s[x] = 0.f;
#pragma unroll
  for (int ss = 0; ss < NS; ++ss) {
    uint4 v = *(const uint4*)(en + (long)(gr * NS + ss) * 64 + (it - 16) * 32 + q * 8);
    unsigned vals[4] = {v.x, v.y, v.z, v.w};
#pragma unroll
    for (int x = 0; x < 4; ++x) {
      s[x * 2]     += bf2f((unsigned short)(vals[x] & 0xFFFF));
      s[x * 2 + 1] += bf2f((unsigned short)(vals[x] >> 16));
    }
  }
  uint4 o;
  o.x = pk2(s[0] * 0.1f, s[1] * 0.1f);
  o.y = pk2(s[2] * 0.1f, s[3] * 0.1f);
  o.z = pk2(s[4] * 0.1f, s[5] * 0.1f);
  o.w = pk2(s[6] * 0.1f, s[7] * 0.1f);
  return o;
}

__global__ __launch_bounds__(256) void gemm3_k(
    const unsigned short* __restrict__ A3, const unsigned short* __restrict__ enew,
    const unsigned short* __restrict__ wt1, float* __restrict__ osum) {
  __shared__ unsigned short sm[10240];
  unsigned short* As = sm;         // [2][2560]
  unsigned short* Bs = sm + 5120;  // [2][2560]
  int tid = threadIdx.x, tile = blockIdx.x;
  int mp = tile & 1, t2 = tile >> 1;
  int n0 = (t2 & 3) * 64, m0 = (t2 >> 2) * 64;
  const unsigned short* Ap = A3 + (long)mp * (512L * 576) + (long)m0 * 576;
  const unsigned short* en = enew + (long)mp * (5120L * 64);
  const unsigned short* Bp = wt1 + (long)(mp * 2 + 1) * 147456 + (long)n0 * 576;

  int row = tid >> 2, q = tid & 3;
  int gr = m0 + row;
  const unsigned short* apt = Ap + (long)row * 576 + q * 8;
  const unsigned short* bpt = Bp + (long)row * 576 + q * 8;

  {
    uint4 a = g3A(apt, en, gr, q, 0);
    uint4 bv = *(const uint4*)bpt;
    *(uint4*)&As[row * 40 + q * 8] = a;
    *(uint4*)&Bs[row * 40 + q * 8] = bv;
  }
  __syncthreads();

  f32x4 acc[2][2];
#pragma unroll
  for (int i = 0; i < 2; ++i)
#pragma unroll
    for (int j = 0; j < 2; ++j) acc[i][j] = (f32x4){0.f, 0.f, 0.f, 0.f};

  int wave = tid >> 6, lane = tid & 63;
  int wm = wave >> 1, wn = wave & 1;
  int quad = lane >> 4, r16 = lane & 15;

  for (int it = 0; it < 18; ++it) {
    uint4 na, nb;
    bool pf = (it + 1 < 18);
    if (pf) {
      na = g3A(apt, en, gr, q, it + 1);
      nb = *(const uint4*)(bpt + (it + 1) * 32);
    }
    int c = it & 1;
    bf16x8 af[2], bfr[2];
#pragma unroll
    for (int i = 0; i < 2; ++i)
      af[i] = *(const bf16x8*)&As[c * 2560 + (wm * 32 + i * 16 + r16) * 40 + quad * 8];
#pragma unroll
    for (int j = 0; j < 2; ++j)
      bfr[j] = *(const bf16x8*)&Bs[c * 2560 + (wn * 32 + j * 16 + r16) * 40 + quad * 8];
#pragma unroll
    for (int i = 0; i < 2; ++i)
#pragma unroll
      for (int j = 0; j < 2; ++j)
        acc[i][j] = __builtin_amdgcn_mfma_f32_16x16x32_bf16(af[i], bfr[j], acc[i][j], 0, 0, 0);
    if (pf) {
      *(uint4*)&As[(c ^ 1) * 2560 + row * 40 + q * 8] = na;
      *(uint4*)&Bs[(c ^ 1) * 2560 + row * 40 + q * 8] = nb;
      __syncthreads();
    }
  }
#pragma unroll
  for (int i = 0; i < 2; ++i)
#pragma unroll
    for (int j = 0; j < 2; ++j)
#pragma unroll
      for (int r = 0; r < 4; ++r) {
        int rr = m0 + wm * 32 + i * 16 + quad * 4 + r;
        int cc = n0 + wn * 32 + j * 16 + r16;
        osum[(long)mp * 131072 + (long)rr * 256 + cc] = acc[i][j][r];
      }
}

// ---- finalize: out = normalize((o0+o1)/2) @ fc_w + fc_b; 4 rows/block ----
__global__ __launch_bounds__(256) void finalize_k(
    const float* __restrict__ osum, const float* __restrict__ fcw,
    const float* __restrict__ fcb, float* __restrict__ out) {
  int tid = threadIdx.x;
  int wave = tid >> 6, l = tid & 63;
  int b = blockIdx.x * 4 + wave;
  const float* o0 = osum;
  const float* o1 = osum + 131072;
  float v[4];
  float ss = 0.f;
#pragma unroll
  for (int k = 0; k < 4; ++k) {
    int j = l + 64 * k;
    v[k] = 0.5f * (o0[(long)b * 256 + j] + o1[(long)b * 256 + j]);
    ss += v[k] * v[k];
  }
#pragma unroll
  for (int off = 32; off > 0; off >>= 1) ss += __shfl_down(ss, off);
  ss = __shfl(ss, 0);
  float sc = 1.f / fmaxf(sqrtf(ss), 1e-12f);
  float p[8];
#pragma unroll
  for (int c = 0; c < 8; ++c) p[c] = 0.f;
#pragma unroll
  for (int k = 0; k < 4; ++k) {
    int j = l + 64 * k;
    float vh = v[k] * sc;
#pragma unroll
    for (int c = 0; c < 8; ++c) p[c] += vh * fcw[j * 8 + c];
  }
#pragma unroll
  for (int off = 32; off > 0; off >>= 1) {
#pragma unroll
    for (int c = 0; c < 8; ++c) p[c] += __shfl_down(p[c], off);
  }
  if (l == 0) {
#pragma unroll
    for (int c = 0; c < 8; ++c) out[b * 8 + c] = p[c] + fcb[c];
  }
}

extern "C" void kernel_launch(void* const* d_in, const int* in_sizes, int n_in,
                              void* d_out, int out_size, void* d_ws, size_t ws_size,
                              hipStream_t stream) {
  const int* ids = (const int*)d_in[0];
  const float* feats = (const float*)d_in[1];
  const int* n0i[2] = {(const int*)d_in[2], (const int*)d_in[4]};
  const int* n1i[2] = {(const int*)d_in[3], (const int*)d_in[5]};
  const int* e0i[2] = {(const int*)d_in[6], (const int*)d_in[8]};
  const int* e1i[2] = {(const int*)d_in[7], (const int*)d_in[9]};
  const float* emb[2] = {(const float*)d_in[10], (const float*)d_in[11]};
  const float* Wself = (const float*)d_in[12];
  const float* Wneigh = (const float*)d_in[13];
  const float* Wedg = (const float*)d_in[14];
  const float* Wec = (const float*)d_in[15];
  const float* bec = (const float*)d_in[16];
  const float* fcw = (const float*)d_in[17];
  const float* fcb = (const float*)d_in[18];
  float* out = (float*)d_out;

  // ---- workspace ----
  float* osum = (float*)d_ws;                               // [2][512][256] f32
  unsigned short* A1b  = (unsigned short*)(osum + 262144);  // [2][5632][576]
  unsigned short* eg0  = A1b + 6488064;                     // [2][5120][64]
  unsigned short* h01  = eg0 + 655360;                      // [2][5632][256]
  unsigned short* enew = h01 + 2883584;                     // [2][5120][64]
  unsigned short* wt1  = enew + 655360;                     // [4][256][576]
  unsigned short* wte  = wt1 + 589824;                      // [2][64][576]
  unsigned short* A3   = wte + 73728;                       // [2][512][576]

  // ---- gather jobs (dual jobs fuse direct-copy + mean over same rows) ----
  GJobs gj; int blk = 0, nj = 0;
  {
    auto add = [&](const float* table, const int* idx, unsigned short* o,
                   int M, int D4, int ns, int ostride, float inv,
                   unsigned short* o2, int ostride2) {
      gj.j[nj] = {table, idx, o, o2, M, D4, ns, ostride, ostride2, blk, inv};
      blk += (M * D4) / 256; ++nj;
    };
    for (int mp = 0; mp < 2; ++mp) {
      unsigned short* Am = A1b + (size_t)mp * 5632 * 576;
      // x0 direct: rows 0..511 cols 0..255
      add(feats, ids, Am, 512, 64, 1, 576, 1.0f, nullptr, 0);
      // n0: mean -> rows 0..511 cols 256..511  AND direct -> rows 512.. cols 0..255
      add(feats, n0i[mp], Am + 256, 512, 64, NS, 576, 0.1f, Am + 512 * 576, 576);
      // n1 mean: rows 512.. cols 256..511
      add(feats, n1i[mp], Am + 512 * 576 + 256, 5120, 64, NS, 576, 0.1f, nullptr, 0);
      // e0: mean -> rows 0..511 cols 512..575  AND direct -> eg0
      add(emb[mp], e0i[mp], Am + 512, 512, 16, NS, 576, 0.1f,
          eg0 + (size_t)mp * 327680, 64);
      // e1 mean: rows 512.. cols 512..575
      add(emb[mp], e1i[mp], Am + 512 * 576 + 512, 5120, 16, NS, 576, 0.1f, nullptr, 0);
    }
  }

  // 1) prep: weight pack + gathers
  gprep_k<<<dim3(PACKB + blk), dim3(256), 0, stream>>>(
      gj, nj, Wself, Wneigh, Wedg, Wec, wt1, wte);

  // 2) layer-0 agg (352 tiles); tees h0 rows into A3
  gemm1_k<<<dim3(352), dim3(256), 0, stream>>>(A1b, wt1, h01, A3);

  // 3) edge GEMM (160 tiles) || h1-means (128 blocks)
  p3_k<<<dim3(288), dim3(256), 0, stream>>>(h01, eg0, wte, bec, enew, A3);

  // 4) layer-1 agg with on-the-fly e-means (64 tiles)
  gemm3_k<<<dim3(64), dim3(256), 0, stream>>>(A3, enew, wt1, osum);

  // 5) metapath mean + L2 normalize + FC
  finalize_k<<<dim3(128), dim3(256), 0, stream>>>(osum, fcw, fcb, out);
}

// Round 5
// 269.542 us; speedup vs baseline: 1.7909x; 1.0092x over previous
//
#include <hip/hip_runtime.h>

#define NS 10
#define PACKB 2592  // (2*2*256*576 + 2*64*576) / 256

typedef __attribute__((ext_vector_type(8))) short bf16x8;
typedef __attribute__((ext_vector_type(4))) float f32x4;

__device__ __forceinline__ float bf2f(unsigned short u) {
  union { unsigned int i; float f; } x;
  x.i = ((unsigned int)u) << 16;
  return x.f;
}
__device__ __forceinline__ unsigned short f2bf(float f) {
  union { float f; unsigned int i; } x; x.f = f;
  unsigned int r = x.i + 0x7FFFu + ((x.i >> 16) & 1u);
  return (unsigned short)(r >> 16);
}
__device__ __forceinline__ unsigned pk2(float a, float b) {
  return (unsigned)f2bf(a) | ((unsigned)f2bf(b) << 16);
}

// ===== gprep: weight pack + gathers; dual jobs write direct rows AND mean ===
struct GJob {
  const float* table; const int* idx;
  unsigned short* out; unsigned short* out2;   // out2: direct rows (dual jobs)
  int M, D4, ns, ostride, ostride2, blk0; float inv;
};
struct GJobs { GJob j[10]; };

__global__ __launch_bounds__(256) void gprep_k(
    GJobs js, int njobs,
    const float* __restrict__ Wself, const float* __restrict__ Wneigh,
    const float* __restrict__ Wedg, const float* __restrict__ Wec,
    unsigned short* __restrict__ wt1, unsigned short* __restrict__ wte) {
  int b = blockIdx.x;
  if (b < PACKB) {
    int t = b * 256 + threadIdx.x;
    const int total1 = 2 * 2 * 256 * 576;
    if (t < total1) {
      int g = t / 147456, r = t - g * 147456;
      int n = r / 576, k = r - n * 576;
      float v;
      if (k < 256) v = Wself[(long)g * 65536 + k * 256 + n];
      else if (k < 512) v = Wneigh[(long)g * 65536 + (k - 256) * 256 + n];
      else v = Wedg[(long)g * 16384 + (k - 512) * 256 + n];
      wt1[t] = f2bf(v);
    } else {
      int t2 = t - total1;  // < 2*64*576
      int mp = t2 / 36864, r = t2 - mp * 36864;
      int n = r / 576, k = r - n * 576;
      wte[t2] = f2bf(Wec[(long)(mp * 2) * 36864 + k * 64 + n]);
    }
    return;
  }
  b -= PACKB;
  int ji = 0;
  for (int k = 1; k < njobs; ++k) if (b >= js.j[k].blk0) ji = k;
  GJob jb = js.j[ji];
  int t = (b - jb.blk0) * 256 + threadIdx.x;
  int m = t / jb.D4, d4 = t - m * jb.D4;
  long D = (long)jb.D4 * 4;
  float ax = 0.f, ay = 0.f, az = 0.f, aw = 0.f;
  if (jb.ns == NS) {
    int ridx[NS];
#pragma unroll
    for (int s = 0; s < NS; ++s) ridx[s] = jb.idx[(long)m * NS + s];
    float4 vv[NS];
#pragma unroll
    for (int s = 0; s < NS; ++s)
      vv[s] = *(const float4*)(jb.table + (long)ridx[s] * D + d4 * 4);
#pragma unroll
    for (int s = 0; s < NS; ++s) {
      ax += vv[s].x; ay += vv[s].y; az += vv[s].z; aw += vv[s].w;
    }
    if (jb.out2) {  // dual: also emit the 10 direct rows (scale 1.0)
#pragma unroll
      for (int s = 0; s < NS; ++s) {
        uint2 o2; o2.x = pk2(vv[s].x, vv[s].y); o2.y = pk2(vv[s].z, vv[s].w);
        *(uint2*)(jb.out2 + (long)(m * NS + s) * jb.ostride2 + d4 * 4) = o2;
      }
    }
  } else {
    long r = (long)jb.idx[m];
    float4 v = *(const float4*)(jb.table + r * D + d4 * 4);
    ax = v.x; ay = v.y; az = v.z; aw = v.w;
  }
  uint2 o; o.x = pk2(ax * jb.inv, ay * jb.inv); o.y = pk2(az * jb.inv, aw * jb.inv);
  *(uint2*)(jb.out + (long)m * jb.ostride + d4 * 4) = o;
}

// ===== GEMM1: h01 = relu(A1b @ WT1[mp][0]); BM=64 BN=64, 2-deep prefetch ====
// Tees rows<512 into A3[mp][512][576] cols 0..255. 704 tiles.
__global__ __launch_bounds__(256) void gemm1_k(
    const unsigned short* __restrict__ A, const unsigned short* __restrict__ wt1,
    unsigned short* __restrict__ C, unsigned short* __restrict__ A3) {
  __shared__ unsigned short As[2][2560];
  __shared__ unsigned short Bs[2][2560];
  int tid = threadIdx.x, tile = blockIdx.x;
  int mp = tile & 1, t2 = tile >> 1;
  int n0 = (t2 & 3) * 64, m0 = (t2 >> 2) * 64;
  const unsigned short* Ap = A + (long)mp * (5632L * 576) + (long)m0 * 576;
  const unsigned short* Bp = wt1 + (long)mp * 2 * 147456 + (long)n0 * 576;
  int row = tid >> 2, q = tid & 3;
  const unsigned short* apt = Ap + (long)row * 576 + q * 8;
  const unsigned short* bpt = Bp + (long)row * 576 + q * 8;

  {  // prologue: stage it=0, issue it=1
    uint4 a0 = *(const uint4*)apt;
    uint4 b0 = *(const uint4*)bpt;
    *(uint4*)&As[0][row * 40 + q * 8] = a0;
    *(uint4*)&Bs[0][row * 40 + q * 8] = b0;
  }
  uint4 an = *(const uint4*)(apt + 32);
  uint4 bn = *(const uint4*)(bpt + 32);
  __syncthreads();

  f32x4 acc[2][2];
#pragma unroll
  for (int i = 0; i < 2; ++i)
#pragma unroll
    for (int j = 0; j < 2; ++j) acc[i][j] = (f32x4){0.f, 0.f, 0.f, 0.f};

  int wave = tid >> 6, lane = tid & 63;
  int wm = wave >> 1, wn = wave & 1;
  int quad = lane >> 4, r16 = lane & 15;

  for (int it = 0; it < 18; ++it) {
    uint4 af_, bf_;
    if (it + 2 < 18) {  // deepest prefetch: issue it+2 now
      af_ = *(const uint4*)(apt + (it + 2) * 32);
      bf_ = *(const uint4*)(bpt + (it + 2) * 32);
    }
    int c = it & 1;
    bf16x8 av[2], bv[2];
#pragma unroll
    for (int i = 0; i < 2; ++i)
      av[i] = *(const bf16x8*)&As[c][(wm * 32 + i * 16 + r16) * 40 + quad * 8];
#pragma unroll
    for (int j = 0; j < 2; ++j)
      bv[j] = *(const bf16x8*)&Bs[c][(wn * 32 + j * 16 + r16) * 40 + quad * 8];
#pragma unroll
    for (int i = 0; i < 2; ++i)
#pragma unroll
      for (int j = 0; j < 2; ++j)
        acc[i][j] = __builtin_amdgcn_mfma_f32_16x16x32_bf16(av[i], bv[j], acc[i][j], 0, 0, 0);
    if (it + 1 < 18) {  // land it+1 (issued last iteration)
      *(uint4*)&As[c ^ 1][row * 40 + q * 8] = an;
      *(uint4*)&Bs[c ^ 1][row * 40 + q * 8] = bn;
      __syncthreads();
    }
    an = af_; bn = bf_;
  }
#pragma unroll
  for (int i = 0; i < 2; ++i)
#pragma unroll
    for (int j = 0; j < 2; ++j)
#pragma unroll
      for (int r = 0; r < 4; ++r) {
        int rr = m0 + wm * 32 + i * 16 + quad * 4 + r;
        int cc = n0 + wn * 32 + j * 16 + r16;
        unsigned short u = f2bf(fmaxf(acc[i][j][r], 0.f));
        C[(long)mp * (5632L * 256) + (long)rr * 256 + cc] = u;
        if (rr < 512)
          A3[(long)mp * (512L * 576) + (long)rr * 576 + cc] = u;
      }
}

// ===== P3: edge GEMM (160 tiles) || h1-means (128 block-jobs) ==============
__device__ __forceinline__ const unsigned short* edgeA(
    const unsigned short* h0, const unsigned short* h1, const unsigned short* eg,
    int ar0, int gr, int q, int it) {
  if (it < 8)  return h0 + (long)ar0 * 256 + it * 32 + q * 8;
  if (it < 16) return h1 + (long)gr * 256 + (it - 8) * 32 + q * 8;
  return eg + (long)gr * 64 + (it - 16) * 32 + q * 8;
}

__device__ void edge_tile(int tile, const unsigned short* h01, const unsigned short* eg0,
                          const unsigned short* wte, const float* bec,
                          unsigned short* enew, unsigned short* sm, int tid) {
  unsigned short* As = sm;         // [2][2560]
  unsigned short* Bs = sm + 5120;  // [2][2560]
  int mp = tile & 1;
  int m0 = (tile >> 1) * 64;
  const unsigned short* h0 = h01 + (long)mp * (5632L * 256);
  const unsigned short* h1 = h0 + 512 * 256;
  const unsigned short* eg = eg0 + (long)mp * (5120L * 64);
  const unsigned short* Bp = wte + (long)mp * 36864;

  int row = tid >> 2, q = tid & 3;
  int gr = m0 + row;
  int ar0 = gr / 10;
  const unsigned short* bpt = Bp + (long)row * 576 + q * 8;

  {
    uint4 a = *(const uint4*)edgeA(h0, h1, eg, ar0, gr, q, 0);
    uint4 bv = *(const uint4*)bpt;
    *(uint4*)&As[row * 40 + q * 8] = a;
    *(uint4*)&Bs[row * 40 + q * 8] = bv;
  }
  uint4 an = *(const uint4*)edgeA(h0, h1, eg, ar0, gr, q, 1);
  uint4 bn = *(const uint4*)(bpt + 32);
  __syncthreads();

  f32x4 acc[2][2];
#pragma unroll
  for (int i = 0; i < 2; ++i)
#pragma unroll
    for (int j = 0; j < 2; ++j) acc[i][j] = (f32x4){0.f, 0.f, 0.f, 0.f};

  int wave = tid >> 6, lane = tid & 63;
  int wm = wave >> 1, wn = wave & 1;
  int quad = lane >> 4, r16 = lane & 15;

  for (int it = 0; it < 18; ++it) {
    uint4 af_, bf_;
    if (it + 2 < 18) {
      af_ = *(const uint4*)edgeA(h0, h1, eg, ar0, gr, q, it + 2);
      bf_ = *(const uint4*)(bpt + (it + 2) * 32);
    }
    int c = it & 1;
    bf16x8 av[2], bv[2];
#pragma unroll
    for (int i = 0; i < 2; ++i)
      av[i] = *(const bf16x8*)&As[c * 2560 + (wm * 32 + i * 16 + r16) * 40 + quad * 8];
#pragma unroll
    for (int j = 0; j < 2; ++j)
      bv[j] = *(const bf16x8*)&Bs[c * 2560 + (wn * 32 + j * 16 + r16) * 40 + quad * 8];
#pragma unroll
    for (int i = 0; i < 2; ++i)
#pragma unroll
      for (int j = 0; j < 2; ++j)
        acc[i][j] = __builtin_amdgcn_mfma_f32_16x16x32_bf16(av[i], bv[j], acc[i][j], 0, 0, 0);
    if (it + 1 < 18) {
      *(uint4*)&As[(c ^ 1) * 2560 + row * 40 + q * 8] = an;
      *(uint4*)&Bs[(c ^ 1) * 2560 + row * 40 + q * 8] = bn;
      __syncthreads();
    }
    an = af_; bn = bf_;
  }
#pragma unroll
  for (int i = 0; i < 2; ++i)
#pragma unroll
    for (int j = 0; j < 2; ++j)
#pragma unroll
      for (int r = 0; r < 4; ++r) {
        int rr = m0 + wm * 32 + i * 16 + quad * 4 + r;
        int cc = wn * 32 + j * 16 + r16;
        float v = tanhf(acc[i][j][r] + bec[mp * 128 + cc]);
        enew[(long)mp * (5120L * 64) + (long)rr * 64 + cc] = f2bf(v);
      }
}

__device__ __forceinline__ void h1mean_item(int t, const unsigned short* h01,
                                            unsigned short* A3) {
  // t in [0, 32768): mp = t>>14, m = (t&16383)>>5, d8 = t&31
  int mp = t >> 14, t14 = t & 16383;
  int m = t14 >> 5, d8 = t14 & 31;
  const unsigned short* h1 = h01 + (long)mp * (5632L * 256) + 512 * 256;
  float s[8];
#pragma unroll
  for (int x = 0; x < 8; ++x) s[x] = 0.f;
#pragma unroll
  for (int ss = 0; ss < NS; ++ss) {
    uint4 v = *(const uint4*)(h1 + (long)(m * NS + ss) * 256 + d8 * 8);
    unsigned vals[4] = {v.x, v.y, v.z, v.w};
#pragma unroll
    for (int x = 0; x < 4; ++x) {
      s[x * 2]     += bf2f((unsigned short)(vals[x] & 0xFFFF));
      s[x * 2 + 1] += bf2f((unsigned short)(vals[x] >> 16));
    }
  }
  uint4 o;
  o.x = pk2(s[0] * 0.1f, s[1] * 0.1f);
  o.y = pk2(s[2] * 0.1f, s[3] * 0.1f);
  o.z = pk2(s[4] * 0.1f, s[5] * 0.1f);
  o.w = pk2(s[6] * 0.1f, s[7] * 0.1f);
  *(uint4*)(A3 + (long)mp * (512L * 576) + (long)m * 576 + 256 + d8 * 8) = o;
}

__global__ __launch_bounds__(256) void p3_k(
    const unsigned short* __restrict__ h01, const unsigned short* __restrict__ eg0,
    const unsigned short* __restrict__ wte, const float* __restrict__ bec,
    unsigned short* __restrict__ enew, unsigned short* __restrict__ A3) {
  __shared__ unsigned short sm[10240];
  int j = blockIdx.x;
  if (j < 160) edge_tile(j, h01, eg0, wte, bec, enew, sm, threadIdx.x);
  else h1mean_item((j - 160) * 256 + threadIdx.x, h01, A3);
}

// ===== GEMM3: osum = [A3 cols 0..511 | mean10(enew)] @ WT1[mp][1] ==========
// BM=64 BN=64, 2-deep; e-mean computed on the fly in the A-stage (it>=16).
__device__ __forceinline__ uint4 g3A(const unsigned short* apt,
                                     const unsigned short* en, int gr, int q, int it) {
  if (it < 16) return *(const uint4*)(apt + it * 32);
  float s[8];
#pragma unroll
  for (int x = 0; x < 8; ++x) s[x] = 0.f;
#pragma unroll
  for (int ss = 0; ss < NS; ++ss) {
    uint4 v = *(const uint4*)(en + (long)(gr * NS + ss) * 64 + (it - 16) * 32 + q * 8);
    unsigned vals[4] = {v.x, v.y, v.z, v.w};
#pragma unroll
    for (int x = 0; x < 4; ++x) {
      s[x * 2]     += bf2f((unsigned short)(vals[x] & 0xFFFF));
      s[x * 2 + 1] += bf2f((unsigned short)(vals[x] >> 16));
    }
  }
  uint4 o;
  o.x = pk2(s[0] * 0.1f, s[1] * 0.1f);
  o.y = pk2(s[2] * 0.1f, s[3] * 0.1f);
  o.z = pk2(s[4] * 0.1f, s[5] * 0.1f);
  o.w = pk2(s[6] * 0.1f, s[7] * 0.1f);
  return o;
}

__global__ __launch_bounds__(256) void gemm3_k(
    const unsigned short* __restrict__ A3, const unsigned short* __restrict__ enew,
    const unsigned short* __restrict__ wt1, float* __restrict__ osum) {
  __shared__ unsigned short As[2][2560];
  __shared__ unsigned short Bs[2][2560];
  int tid = threadIdx.x, tile = blockIdx.x;
  int mp = tile & 1, t2 = tile >> 1;
  int n0 = (t2 & 3) * 64, m0 = (t2 >> 2) * 64;
  const unsigned short* Ap = A3 + (long)mp * (512L * 576) + (long)m0 * 576;
  const unsigned short* en = enew + (long)mp * (5120L * 64);
  const unsigned short* Bp = wt1 + (long)(mp * 2 + 1) * 147456 + (long)n0 * 576;

  int row = tid >> 2, q = tid & 3;
  int gr = m0 + row;
  const unsigned short* apt = Ap + (long)row * 576 + q * 8;
  const unsigned short* bpt = Bp + (long)row * 576 + q * 8;

  {
    uint4 a = g3A(apt, en, gr, q, 0);
    uint4 bv = *(const uint4*)bpt;
    *(uint4*)&As[0][row * 40 + q * 8] = a;
    *(uint4*)&Bs[0][row * 40 + q * 8] = bv;
  }
  uint4 an = g3A(apt, en, gr, q, 1);
  uint4 bn = *(const uint4*)(bpt + 32);
  __syncthreads();

  f32x4 acc[2][2];
#pragma unroll
  for (int i = 0; i < 2; ++i)
#pragma unroll
    for (int j = 0; j < 2; ++j) acc[i][j] = (f32x4){0.f, 0.f, 0.f, 0.f};

  int wave = tid >> 6, lane = tid & 63;
  int wm = wave >> 1, wn = wave & 1;
  int quad = lane >> 4, r16 = lane & 15;

  for (int it = 0; it < 18; ++it) {
    uint4 af_, bf_;
    if (it + 2 < 18) {
      af_ = g3A(apt, en, gr, q, it + 2);
      bf_ = *(const uint4*)(bpt + (it + 2) * 32);
    }
    int c = it & 1;
    bf16x8 av[2], bv[2];
#pragma unroll
    for (int i = 0; i < 2; ++i)
      av[i] = *(const bf16x8*)&As[c][(wm * 32 + i * 16 + r16) * 40 + quad * 8];
#pragma unroll
    for (int j = 0; j < 2; ++j)
      bv[j] = *(const bf16x8*)&Bs[c][(wn * 32 + j * 16 + r16) * 40 + quad * 8];
#pragma unroll
    for (int i = 0; i < 2; ++i)
#pragma unroll
      for (int j = 0; j < 2; ++j)
        acc[i][j] = __builtin_amdgcn_mfma_f32_16x16x32_bf16(av[i], bv[j], acc[i][j], 0, 0, 0);
    if (it + 1 < 18) {
      *(uint4*)&As[c ^ 1][row * 40 + q * 8] = an;
      *(uint4*)&Bs[c ^ 1][row * 40 + q * 8] = bn;
      __syncthreads();
    }
    an = af_; bn = bf_;
  }
#pragma unroll
  for (int i = 0; i < 2; ++i)
#pragma unroll
    for (int j = 0; j < 2; ++j)
#pragma unroll
      for (int r = 0; r < 4; ++r) {
        int rr = m0 + wm * 32 + i * 16 + quad * 4 + r;
        int cc = n0 + wn * 32 + j * 16 + r16;
        osum[(long)mp * 131072 + (long)rr * 256 + cc] = acc[i][j][r];
      }
}

// ---- finalize: out = normalize((o0+o1)/2) @ fc_w + fc_b; 4 rows/block ----
__global__ __launch_bounds__(256) void finalize_k(
    const float* __restrict__ osum, const float* __restrict__ fcw,
    const float* __restrict__ fcb, float* __restrict__ out) {
  int tid = threadIdx.x;
  int wave = tid >> 6, l = tid & 63;
  int b = blockIdx.x * 4 + wave;
  const float* o0 = osum;
  const float* o1 = osum + 131072;
  float v[4];
  float ss = 0.f;
#pragma unroll
  for (int k = 0; k < 4; ++k) {
    int j = l + 64 * k;
    v[k] = 0.5f * (o0[(long)b * 256 + j] + o1[(long)b * 256 + j]);
    ss += v[k] * v[k];
  }
#pragma unroll
  for (int off = 32; off > 0; off >>= 1) ss += __shfl_down(ss, off);
  ss = __shfl(ss, 0);
  float sc = 1.f / fmaxf(sqrtf(ss), 1e-12f);
  float p[8];
#pragma unroll
  for (int c = 0; c < 8; ++c) p[c] = 0.f;
#pragma unroll
  for (int k = 0; k < 4; ++k) {
    int j = l + 64 * k;
    float vh = v[k] * sc;
#pragma unroll
    for (int c = 0; c < 8; ++c) p[c] += vh * fcw[j * 8 + c];
  }
#pragma unroll
  for (int off = 32; off > 0; off >>= 1) {
#pragma unroll
    for (int c = 0; c < 8; ++c) p[c] += __shfl_down(p[c], off);
  }
  if (l == 0) {
#pragma unroll
    for (int c = 0; c < 8; ++c) out[b * 8 + c] = p[c] + fcb[c];
  }
}

extern "C" void kernel_launch(void* const* d_in, const int* in_sizes, int n_in,
                              void* d_out, int out_size, void* d_ws, size_t ws_size,
                              hipStream_t stream) {
  const int* ids = (const int*)d_in[0];
  const float* feats = (const float*)d_in[1];
  const int* n0i[2] = {(const int*)d_in[2], (const int*)d_in[4]};
  const int* n1i[2] = {(const int*)d_in[3], (const int*)d_in[5]};
  const int* e0i[2] = {(const int*)d_in[6], (const int*)d_in[8]};
  const int* e1i[2] = {(const int*)d_in[7], (const int*)d_in[9]};
  const float* emb[2] = {(const float*)d_in[10], (const float*)d_in[11]};
  const float* Wself = (const float*)d_in[12];
  const float* Wneigh = (const float*)d_in[13];
  const float* Wedg = (const float*)d_in[14];
  const float* Wec = (const float*)d_in[15];
  const float* bec = (const float*)d_in[16];
  const float* fcw = (const float*)d_in[17];
  const float* fcb = (const float*)d_in[18];
  float* out = (float*)d_out;

  // ---- workspace ----
  float* osum = (float*)d_ws;                               // [2][512][256] f32
  unsigned short* A1b  = (unsigned short*)(osum + 262144);  // [2][5632][576]
  unsigned short* eg0  = A1b + 6488064;                     // [2][5120][64]
  unsigned short* h01  = eg0 + 655360;                      // [2][5632][256]
  unsigned short* enew = h01 + 2883584;                     // [2][5120][64]
  unsigned short* wt1  = enew + 655360;                     // [4][256][576]
  unsigned short* wte  = wt1 + 589824;                      // [2][64][576]
  unsigned short* A3   = wte + 73728;                       // [2][512][576]

  // ---- gather jobs (dual jobs fuse direct-copy + mean over same rows) ----
  GJobs gj; int blk = 0, nj = 0;
  {
    auto add = [&](const float* table, const int* idx, unsigned short* o,
                   int M, int D4, int ns, int ostride, float inv,
                   unsigned short* o2, int ostride2) {
      gj.j[nj] = {table, idx, o, o2, M, D4, ns, ostride, ostride2, blk, inv};
      blk += (M * D4) / 256; ++nj;
    };
    for (int mp = 0; mp < 2; ++mp) {
      unsigned short* Am = A1b + (size_t)mp * 5632 * 576;
      add(feats, ids, Am, 512, 64, 1, 576, 1.0f, nullptr, 0);
      add(feats, n0i[mp], Am + 256, 512, 64, NS, 576, 0.1f, Am + 512 * 576, 576);
      add(feats, n1i[mp], Am + 512 * 576 + 256, 5120, 64, NS, 576, 0.1f, nullptr, 0);
      add(emb[mp], e0i[mp], Am + 512, 512, 16, NS, 576, 0.1f,
          eg0 + (size_t)mp * 327680, 64);
      add(emb[mp], e1i[mp], Am + 512 * 576 + 512, 5120, 16, NS, 576, 0.1f, nullptr, 0);
    }
  }

  // 1) prep: weight pack + gathers
  gprep_k<<<dim3(PACKB + blk), dim3(256), 0, stream>>>(
      gj, nj, Wself, Wneigh, Wedg, Wec, wt1, wte);

  // 2) layer-0 agg (704 tiles); tees h0 rows into A3
  gemm1_k<<<dim3(704), dim3(256), 0, stream>>>(A1b, wt1, h01, A3);

  // 3) edge GEMM (160 tiles) || h1-means (128 blocks)
  p3_k<<<dim3(288), dim3(256), 0, stream>>>(h01, eg0, wte, bec, enew, A3);

  // 4) layer-1 agg with on-the-fly e-means (64 tiles)
  gemm3_k<<<dim3(64), dim3(256), 0, stream>>>(A3, enew, wt1, osum);

  // 5) metapath mean + L2 normalize + FC
  finalize_k<<<dim3(128), dim3(256), 0, stream>>>(osum, fcw, fcb, out);
}